// Round 1
// baseline (189.938 us; speedup 1.0000x reference)
//
#include <hip/hip_runtime.h>

#define N_NODES 20000
#define N_EDGES 640000
#define F 128
#define CAP 128          // max in-degree; deg ~ Binomial(640K, 1/20K); expected max deg ~57
#define GEMM_BLOCKS (N_NODES / 32)     // 625
#define SCAT_BLOCKS 2560               // 320 per XCD residue class
#define SCAT_STRIDE (SCAT_BLOCKS / 8 * 256)   // 81920 edges per sweep per class
#define NODES_PER_XCD (N_NODES / 8)    // 2500
#define AGG_BLOCKS 2504                // 313 per residue class (last wave-set guarded)

// HISTORY:
//  r2/r3: fused GEMM+proj epilogue spilled (64-VGPR cap; VGPR=256 + 565 MB scratch).
//  r4: de-fused: 218. r5: gather-into-GEMM fusion -> occ 22.6%: 227 (revert).
//  r6: mean-linearity reorder (GEMM first): 215. r7: gemm1+bucket merge: 213.
//  r8: uint16 bucket + slice-partitioned agg (4 x 32-float slices, bid%8 XCD swizzle): 203.
//  r9: proj fused into agg2 via atomicAdd: 207.5 (regression, REVERTED).
//  r10: register-held index lists (shfl-distributed) + 2 nodes/wave agg: 187.4.
//  r11: XCD-LOCAL SCATTER: partition dst-nodes into 8 ranges of 2500; scatter
//       blocks grouped by bid&7 only dirty their own 640 KB bucket region: 185.9.
//  r12: GROUP-PER-NODE AGG. slice_agg was issue-bound: ~72 wave-instrs per
//       node-slice task, dominated by shfl index distribution + 3-round
//       shfl_xor reduce (LDS-pipe, ~30cy dependent chains), stores from 8/64
//       lanes. New: one 8-lane group owns one full node-slice (8 lanes x
//       float4 = 32 floats); neighbor indices broadcast-loaded straight from
//       the bucket list (same-address load in group = 1 fetch + HW broadcast).
//       Zero cross-lane ops, full-wave stores, ~26 instrs/task, 4x fewer
//       waves. Same slice->XCD residency (address-partitioned).

// ---------------------------------------------------------------------------
// Merged: blocks [0,625) y = A @ W (proven 44-VGPR tile); blocks [625,3185)
// XCD-local scatter of edges into per-destination uint16 buckets.
// ---------------------------------------------------------------------------
__global__ __launch_bounds__(256)
void gemm_bucket_kernel(const float* __restrict__ A, const float* __restrict__ W,
                        float* __restrict__ C,
                        const int* __restrict__ src, const int* __restrict__ dst,
                        int* __restrict__ cnt, unsigned short* __restrict__ bucket) {
    __shared__ float As[32][F + 4];
    int tid = threadIdx.x;
    int bid = blockIdx.x;

    if (bid >= GEMM_BLOCKS) {
        int s   = bid - GEMM_BLOCKS;   // 0..2559
        int g   = bid & 7;             // XCD residue of the RAW block id
        int idx = s >> 3;              // 0..319 within this residue class
        int lo  = g * NODES_PER_XCD;
        int hi  = lo + NODES_PER_XCD;
        for (int e = idx * 256 + tid; e < N_EDGES; e += SCAT_STRIDE) {
            int d  = dst[e];           // coalesced
            int sv = src[e];           // coalesced
            if (d >= lo && d < hi) {   // ~1/8 of lanes active
                int pos = atomicAdd(&cnt[d], 1);
                if (pos < CAP) bucket[(size_t)d * CAP + pos] = (unsigned short)sv;
            }
        }
        return;
    }

    int row0 = bid * 32;
    const float4* A4 = (const float4*)(A + (size_t)row0 * F);
    for (int i = tid; i < 32 * 32; i += 256) {
        float4 v = A4[i];
        int r = i >> 5, c4 = (i & 31) * 4;
        *(float4*)&As[r][c4] = v;
    }
    __syncthreads();

    int tx = tid & 31, ty = tid >> 5;
    int c0 = tx * 4, r0 = ty * 4;
    float acc[4][4] = {};

    for (int k = 0; k < F; k += 4) {
        float4 a4[4];
#pragma unroll
        for (int i = 0; i < 4; ++i) a4[i] = *(const float4*)&As[r0 + i][k];
#pragma unroll
        for (int u = 0; u < 4; ++u) {
            float4 w = *(const float4*)(W + (size_t)(k + u) * F + c0);
#pragma unroll
            for (int i = 0; i < 4; ++i) {
                float a = (u == 0) ? a4[i].x : (u == 1) ? a4[i].y : (u == 2) ? a4[i].z : a4[i].w;
                acc[i][0] += a * w.x;
                acc[i][1] += a * w.y;
                acc[i][2] += a * w.z;
                acc[i][3] += a * w.w;
            }
        }
    }

#pragma unroll
    for (int i = 0; i < 4; ++i) {
        float4 o;
        o.x = acc[i][0]; o.y = acc[i][1]; o.z = acc[i][2]; o.w = acc[i][3];
        *(float4*)(C + (size_t)(row0 + r0 + i) * F + c0) = o;
    }
}

// ---------------------------------------------------------------------------
// Plain GEMM (layer 2): C = A @ W.
// ---------------------------------------------------------------------------
__global__ __launch_bounds__(256)
void gemm_kernel(const float* __restrict__ A, const float* __restrict__ W,
                 float* __restrict__ C) {
    __shared__ float As[32][F + 4];
    int tid  = threadIdx.x;
    int row0 = blockIdx.x * 32;

    const float4* A4 = (const float4*)(A + (size_t)row0 * F);
    for (int i = tid; i < 32 * 32; i += 256) {
        float4 v = A4[i];
        int r = i >> 5, c4 = (i & 31) * 4;
        *(float4*)&As[r][c4] = v;
    }
    __syncthreads();

    int tx = tid & 31, ty = tid >> 5;
    int c0 = tx * 4, r0 = ty * 4;
    float acc[4][4] = {};

    for (int k = 0; k < F; k += 4) {
        float4 a4[4];
#pragma unroll
        for (int i = 0; i < 4; ++i) a4[i] = *(const float4*)&As[r0 + i][k];
#pragma unroll
        for (int u = 0; u < 4; ++u) {
            float4 w = *(const float4*)(W + (size_t)(k + u) * F + c0);
#pragma unroll
            for (int i = 0; i < 4; ++i) {
                float a = (u == 0) ? a4[i].x : (u == 1) ? a4[i].y : (u == 2) ? a4[i].z : a4[i].w;
                acc[i][0] += a * w.x;
                acc[i][1] += a * w.y;
                acc[i][2] += a * w.z;
                acc[i][3] += a * w.w;
            }
        }
    }

#pragma unroll
    for (int i = 0; i < 4; ++i) {
        float4 o;
        o.x = acc[i][0]; o.y = acc[i][1]; o.z = acc[i][2]; o.w = acc[i][3];
        *(float4*)(C + (size_t)(row0 + r0 + i) * F + c0) = o;
    }
}

// ---------------------------------------------------------------------------
// Group-per-node slice aggregation + bias + relu:
//   out[n, slice] = relu(mean_{j in nbrs(n)} y[j, slice] + b[slice])
// One 8-lane group owns one node's full 32-float slice (8 lanes x float4).
// Neighbor indices are broadcast-loaded from the bucket list (all 8 lanes of
// a group read the same address -> 1 fetch + HW broadcast). No cross-lane
// ops at all; full-wave stores. 8 nodes per wave, 32 per block.
// Grid AGG_BLOCKS x 256. g = bid&7 -> XCD heuristic; slice = g&3 (2.56 MB
// slice fits the 4 MB XCD L2); partition is by ADDRESS so correctness never
// depends on the bid%8->XCD mapping.
// ---------------------------------------------------------------------------
__global__ __launch_bounds__(256)
void slice_agg_kernel(const float* __restrict__ y, const int* __restrict__ cnt,
                      const unsigned short* __restrict__ bucket,
                      const float* __restrict__ b, float* __restrict__ out) {
    int bid   = blockIdx.x;
    int g     = bid & 7;
    int i     = bid >> 3;          // 0..312
    int slice = g & 3;
    int jj    = i * 2 + (g >> 2);  // 0..625 (625 -> guarded out)
    int wave  = threadIdx.x >> 6;
    int lane  = threadIdx.x & 63;
    int r     = lane >> 3;         // group id: which node
    int c4    = lane & 7;          // float4 column within slice

    int node_base = jj * 32 + wave * 8;
    if (node_base >= N_NODES) return;   // whole wave uniform (20000 % 8 == 0)
    int node = node_base + r;

    int deg = cnt[node];
    int d   = deg < CAP ? deg : CAP;
    const int* lst = (const int*)(bucket + (size_t)node * CAP);  // 2 idx / word

    const float4* fb = (const float4*)y + slice * 8 + c4;   // row stride 32 float4

    float4 acc; acc.x = acc.y = acc.z = acc.w = 0.f;
    int c = 0;
    for (; c + 4 <= d; c += 4) {
        int w0 = lst[c >> 1];
        int w1 = lst[(c >> 1) + 1];
        int i0 = w0 & 0xffff;
        int i1 = (w0 >> 16) & 0xffff;
        int i2 = w1 & 0xffff;
        int i3 = (w1 >> 16) & 0xffff;
        float4 v0 = fb[(size_t)i0 * 32];
        float4 v1 = fb[(size_t)i1 * 32];
        float4 v2 = fb[(size_t)i2 * 32];
        float4 v3 = fb[(size_t)i3 * 32];
        acc.x += (v0.x + v1.x) + (v2.x + v3.x);
        acc.y += (v0.y + v1.y) + (v2.y + v3.y);
        acc.z += (v0.z + v1.z) + (v2.z + v3.z);
        acc.w += (v0.w + v1.w) + (v2.w + v3.w);
    }
    for (; c < d; ++c) {
        int w   = lst[c >> 1];
        int idx = (c & 1) ? ((w >> 16) & 0xffff) : (w & 0xffff);
        float4 v = fb[(size_t)idx * 32];
        acc.x += v.x; acc.y += v.y; acc.z += v.z; acc.w += v.w;
    }

    float4 bv = ((const float4*)b)[slice * 8 + c4];
    float inv = 1.0f / fmaxf((float)deg, 1.0f);
    float4 o;
    o.x = fmaxf(acc.x * inv + bv.x, 0.f);
    o.y = fmaxf(acc.y * inv + bv.y, 0.f);
    o.z = fmaxf(acc.z * inv + bv.z, 0.f);
    o.w = fmaxf(acc.w * inv + bv.w, 0.f);
    ((float4*)out)[(size_t)node * 32 + slice * 8 + c4] = o;
}

// ---------------------------------------------------------------------------
// out[N x 2] = h[N x 128] @ W3[128 x 2] + b3. One wave per node, shuffle
// reduce. Proven cheap (never in any top-5).
// ---------------------------------------------------------------------------
__global__ __launch_bounds__(256)
void final_kernel(const float* __restrict__ h, const float* __restrict__ W3,
                  const float* __restrict__ b3, float* __restrict__ out) {
    int wid  = (blockIdx.x * blockDim.x + threadIdx.x) >> 6;
    int lane = threadIdx.x & 63;
    if (wid >= N_NODES) return;
    float2 v = ((const float2*)h)[(size_t)wid * 64 + lane];
    float4 w = ((const float4*)W3)[lane];
    float a0 = v.x * w.x + v.y * w.z;
    float a1 = v.x * w.y + v.y * w.w;
#pragma unroll
    for (int off = 32; off > 0; off >>= 1) {
        a0 += __shfl_down(a0, off);
        a1 += __shfl_down(a1, off);
    }
    if (lane == 0) {
        out[(size_t)wid * 2]     = a0 + b3[0];
        out[(size_t)wid * 2 + 1] = a1 + b3[1];
    }
}

// ---------------------------------------------------------------------------
extern "C" void kernel_launch(void* const* d_in, const int* in_sizes, int n_in,
                              void* d_out, int out_size, void* d_ws, size_t ws_size,
                              hipStream_t stream) {
    const float* x   = (const float*)d_in[0];
    const int*   ei  = (const int*)d_in[1];
    const int*   src = ei;
    const int*   dst = ei + N_EDGES;
    const float* W1 = (const float*)d_in[2];
    const float* b1 = (const float*)d_in[3];
    const float* W2 = (const float*)d_in[4];
    const float* b2 = (const float*)d_in[5];
    const float* W3 = (const float*)d_in[6];
    const float* b3 = (const float*)d_in[7];
    float* out = (float*)d_out;

    char* base = (char*)d_ws;
    size_t off = 0;
    auto take = [&](size_t bytes) -> char* {
        char* p = base + off;
        off += (bytes + 255) & ~(size_t)255;
        return p;
    };
    int*            cnt    = (int*)           take(N_NODES * sizeof(int));
    unsigned short* bucket = (unsigned short*)take((size_t)N_NODES * CAP * sizeof(unsigned short));
    float*          y      = (float*)         take((size_t)N_NODES * F * sizeof(float));
    float*          h      = (float*)         take((size_t)N_NODES * F * sizeof(float));

    hipMemsetAsync(cnt, 0, N_NODES * sizeof(int), stream);

    // layer 1 GEMM (y = x@W1) overlapped with XCD-local uint16 bucket build
    gemm_bucket_kernel<<<GEMM_BLOCKS + SCAT_BLOCKS, 256, 0, stream>>>(
        x, W1, y, src, dst, cnt, bucket);
    // h = relu(mean(y) + b1)
    slice_agg_kernel<<<AGG_BLOCKS, 256, 0, stream>>>(y, cnt, bucket, b1, h);
    // y = h @ W2
    gemm_kernel<<<N_NODES / 32, 256, 0, stream>>>(h, W2, y);
    // h = relu(mean(y) + b2)
    slice_agg_kernel<<<AGG_BLOCKS, 256, 0, stream>>>(y, cnt, bucket, b2, h);
    // out = h @ W3 + b3
    final_kernel<<<(N_NODES * 64) / 256, 256, 0, stream>>>(h, W3, b3, out);
}

// Round 2
// 187.589 us; speedup vs baseline: 1.0125x; 1.0125x over previous
//
#include <hip/hip_runtime.h>

#define N_NODES 20000
#define N_EDGES 640000
#define F 128
#define CAP 128          // max in-degree; deg ~ Binomial(640K, 1/20K); expected max deg ~57
#define GEMM_BLOCKS (N_NODES / 32)     // 625
#define SCAT_BLOCKS 2560               // 320 per XCD residue class
#define SCAT_STRIDE (SCAT_BLOCKS / 8 * 256)   // 81920 edges per sweep per class
#define NODES_PER_XCD (N_NODES / 8)    // 2500
#define AGG_BLOCKS 2504                // 313 per residue class (last wave-set guarded)

// HISTORY:
//  r2/r3: fused GEMM+proj epilogue spilled (64-VGPR cap; VGPR=256 + 565 MB scratch).
//  r4: de-fused: 218. r5: gather-into-GEMM fusion -> occ 22.6%: 227 (revert).
//  r6: mean-linearity reorder (GEMM first): 215. r7: gemm1+bucket merge: 213.
//  r8: uint16 bucket + slice-partitioned agg (4 x 32-float slices, bid%8 XCD swizzle): 203.
//  r9: proj fused into agg2 via atomicAdd: 207.5 (regression, REVERTED).
//  r10: register-held index lists (shfl-distributed) + 2 nodes/wave agg: 187.4.
//  r11: XCD-LOCAL SCATTER (address-partitioned dst ranges): 185.9.
//  r12: group-per-node agg (8-lane group owns a node-slice, no cross-lane ops):
//       189.9 — NEUTRAL. Post-mortem: both r10/r12 fetch 1 KB/gather-instr;
//       agg is LATENCY-bound not issue-bound (L2-BW floor 9.5 us vs ~40 us
//       actual; only 4 gathers in flight behind a dependent index load;
//       max-of-8-degree trip count +31% issued gathers ate the instr savings).
//  r13: MLP ATTACK. int4 index load (8 idx / 1 load latency) + 8-deep
//       independent gather unroll (2x in-flight) + dual accumulators.
//       VGPR kept <=64 to hold the 8-waves/SIMD occupancy tier.

// ---------------------------------------------------------------------------
// Merged: blocks [0,625) y = A @ W (proven 44-VGPR tile); blocks [625,3185)
// XCD-local scatter of edges into per-destination uint16 buckets.
// ---------------------------------------------------------------------------
__global__ __launch_bounds__(256)
void gemm_bucket_kernel(const float* __restrict__ A, const float* __restrict__ W,
                        float* __restrict__ C,
                        const int* __restrict__ src, const int* __restrict__ dst,
                        int* __restrict__ cnt, unsigned short* __restrict__ bucket) {
    __shared__ float As[32][F + 4];
    int tid = threadIdx.x;
    int bid = blockIdx.x;

    if (bid >= GEMM_BLOCKS) {
        int s   = bid - GEMM_BLOCKS;   // 0..2559
        int g   = bid & 7;             // XCD residue of the RAW block id
        int idx = s >> 3;              // 0..319 within this residue class
        int lo  = g * NODES_PER_XCD;
        int hi  = lo + NODES_PER_XCD;
        for (int e = idx * 256 + tid; e < N_EDGES; e += SCAT_STRIDE) {
            int d  = dst[e];           // coalesced
            int sv = src[e];           // coalesced
            if (d >= lo && d < hi) {   // ~1/8 of lanes active
                int pos = atomicAdd(&cnt[d], 1);
                if (pos < CAP) bucket[(size_t)d * CAP + pos] = (unsigned short)sv;
            }
        }
        return;
    }

    int row0 = bid * 32;
    const float4* A4 = (const float4*)(A + (size_t)row0 * F);
    for (int i = tid; i < 32 * 32; i += 256) {
        float4 v = A4[i];
        int r = i >> 5, c4 = (i & 31) * 4;
        *(float4*)&As[r][c4] = v;
    }
    __syncthreads();

    int tx = tid & 31, ty = tid >> 5;
    int c0 = tx * 4, r0 = ty * 4;
    float acc[4][4] = {};

    for (int k = 0; k < F; k += 4) {
        float4 a4[4];
#pragma unroll
        for (int i = 0; i < 4; ++i) a4[i] = *(const float4*)&As[r0 + i][k];
#pragma unroll
        for (int u = 0; u < 4; ++u) {
            float4 w = *(const float4*)(W + (size_t)(k + u) * F + c0);
#pragma unroll
            for (int i = 0; i < 4; ++i) {
                float a = (u == 0) ? a4[i].x : (u == 1) ? a4[i].y : (u == 2) ? a4[i].z : a4[i].w;
                acc[i][0] += a * w.x;
                acc[i][1] += a * w.y;
                acc[i][2] += a * w.z;
                acc[i][3] += a * w.w;
            }
        }
    }

#pragma unroll
    for (int i = 0; i < 4; ++i) {
        float4 o;
        o.x = acc[i][0]; o.y = acc[i][1]; o.z = acc[i][2]; o.w = acc[i][3];
        *(float4*)(C + (size_t)(row0 + r0 + i) * F + c0) = o;
    }
}

// ---------------------------------------------------------------------------
// Plain GEMM (layer 2): C = A @ W.
// ---------------------------------------------------------------------------
__global__ __launch_bounds__(256)
void gemm_kernel(const float* __restrict__ A, const float* __restrict__ W,
                 float* __restrict__ C) {
    __shared__ float As[32][F + 4];
    int tid  = threadIdx.x;
    int row0 = blockIdx.x * 32;

    const float4* A4 = (const float4*)(A + (size_t)row0 * F);
    for (int i = tid; i < 32 * 32; i += 256) {
        float4 v = A4[i];
        int r = i >> 5, c4 = (i & 31) * 4;
        *(float4*)&As[r][c4] = v;
    }
    __syncthreads();

    int tx = tid & 31, ty = tid >> 5;
    int c0 = tx * 4, r0 = ty * 4;
    float acc[4][4] = {};

    for (int k = 0; k < F; k += 4) {
        float4 a4[4];
#pragma unroll
        for (int i = 0; i < 4; ++i) a4[i] = *(const float4*)&As[r0 + i][k];
#pragma unroll
        for (int u = 0; u < 4; ++u) {
            float4 w = *(const float4*)(W + (size_t)(k + u) * F + c0);
#pragma unroll
            for (int i = 0; i < 4; ++i) {
                float a = (u == 0) ? a4[i].x : (u == 1) ? a4[i].y : (u == 2) ? a4[i].z : a4[i].w;
                acc[i][0] += a * w.x;
                acc[i][1] += a * w.y;
                acc[i][2] += a * w.z;
                acc[i][3] += a * w.w;
            }
        }
    }

#pragma unroll
    for (int i = 0; i < 4; ++i) {
        float4 o;
        o.x = acc[i][0]; o.y = acc[i][1]; o.z = acc[i][2]; o.w = acc[i][3];
        *(float4*)(C + (size_t)(row0 + r0 + i) * F + c0) = o;
    }
}

// ---------------------------------------------------------------------------
// Group-per-node slice aggregation + bias + relu:
//   out[n, slice] = relu(mean_{j in nbrs(n)} y[j, slice] + b[slice])
// One 8-lane group owns one node's full 32-float slice (8 lanes x float4).
// r13: latency-bound fix — one int4 index load yields 8 indices (single load
// latency), feeding 8 INDEPENDENT 128-B gathers kept in flight (2x the MLP
// of r12's 4-deep chunk). Dual accumulators split the dependent add chain.
// Grid AGG_BLOCKS x 256. g = bid&7 -> XCD heuristic; slice = g&3 (2.56 MB
// slice fits the 4 MB XCD L2); partition is by ADDRESS so correctness never
// depends on the bid%8->XCD mapping.
// ---------------------------------------------------------------------------
__global__ __launch_bounds__(256)
void slice_agg_kernel(const float* __restrict__ y, const int* __restrict__ cnt,
                      const unsigned short* __restrict__ bucket,
                      const float* __restrict__ b, float* __restrict__ out) {
    int bid   = blockIdx.x;
    int g     = bid & 7;
    int i     = bid >> 3;          // 0..312
    int slice = g & 3;
    int jj    = i * 2 + (g >> 2);  // 0..625 (625 -> guarded out)
    int wave  = threadIdx.x >> 6;
    int lane  = threadIdx.x & 63;
    int r     = lane >> 3;         // group id: which node
    int c4    = lane & 7;          // float4 column within slice

    int node_base = jj * 32 + wave * 8;
    if (node_base >= N_NODES) return;   // whole wave uniform (20000 % 8 == 0)
    int node = node_base + r;

    int deg = cnt[node];
    int d   = deg < CAP ? deg : CAP;
    const int4* lst4 = (const int4*)(bucket + (size_t)node * CAP);  // 8 idx / int4
    const int*  lst  = (const int*)lst4;                            // 2 idx / word

    const float4* fb = (const float4*)y + slice * 8 + c4;   // row stride 32 float4

    float4 acc0; acc0.x = acc0.y = acc0.z = acc0.w = 0.f;
    float4 acc1; acc1.x = acc1.y = acc1.z = acc1.w = 0.f;
    int c = 0;
    for (; c + 8 <= d; c += 8) {
        int4 w = lst4[c >> 3];                 // 8 indices, one load latency
        int i0 = w.x & 0xffff, i1 = (w.x >> 16) & 0xffff;
        int i2 = w.y & 0xffff, i3 = (w.y >> 16) & 0xffff;
        int i4 = w.z & 0xffff, i5 = (w.z >> 16) & 0xffff;
        int i6 = w.w & 0xffff, i7 = (w.w >> 16) & 0xffff;
        float4 v0 = fb[(size_t)i0 * 32];       // 8 independent 128-B gathers
        float4 v1 = fb[(size_t)i1 * 32];
        float4 v2 = fb[(size_t)i2 * 32];
        float4 v3 = fb[(size_t)i3 * 32];
        float4 v4 = fb[(size_t)i4 * 32];
        float4 v5 = fb[(size_t)i5 * 32];
        float4 v6 = fb[(size_t)i6 * 32];
        float4 v7 = fb[(size_t)i7 * 32];
        acc0.x += (v0.x + v1.x) + (v2.x + v3.x);
        acc0.y += (v0.y + v1.y) + (v2.y + v3.y);
        acc0.z += (v0.z + v1.z) + (v2.z + v3.z);
        acc0.w += (v0.w + v1.w) + (v2.w + v3.w);
        acc1.x += (v4.x + v5.x) + (v6.x + v7.x);
        acc1.y += (v4.y + v5.y) + (v6.y + v7.y);
        acc1.z += (v4.z + v5.z) + (v6.z + v7.z);
        acc1.w += (v4.w + v5.w) + (v6.w + v7.w);
    }
    for (; c < d; ++c) {
        int w   = lst[c >> 1];
        int idx = (c & 1) ? ((w >> 16) & 0xffff) : (w & 0xffff);
        float4 v = fb[(size_t)idx * 32];
        acc0.x += v.x; acc0.y += v.y; acc0.z += v.z; acc0.w += v.w;
    }
    acc0.x += acc1.x; acc0.y += acc1.y; acc0.z += acc1.z; acc0.w += acc1.w;

    float4 bv = ((const float4*)b)[slice * 8 + c4];
    float inv = 1.0f / fmaxf((float)deg, 1.0f);
    float4 o;
    o.x = fmaxf(acc0.x * inv + bv.x, 0.f);
    o.y = fmaxf(acc0.y * inv + bv.y, 0.f);
    o.z = fmaxf(acc0.z * inv + bv.z, 0.f);
    o.w = fmaxf(acc0.w * inv + bv.w, 0.f);
    ((float4*)out)[(size_t)node * 32 + slice * 8 + c4] = o;
}

// ---------------------------------------------------------------------------
// out[N x 2] = h[N x 128] @ W3[128 x 2] + b3. One wave per node, shuffle
// reduce. Proven cheap (never in any top-5).
// ---------------------------------------------------------------------------
__global__ __launch_bounds__(256)
void final_kernel(const float* __restrict__ h, const float* __restrict__ W3,
                  const float* __restrict__ b3, float* __restrict__ out) {
    int wid  = (blockIdx.x * blockDim.x + threadIdx.x) >> 6;
    int lane = threadIdx.x & 63;
    if (wid >= N_NODES) return;
    float2 v = ((const float2*)h)[(size_t)wid * 64 + lane];
    float4 w = ((const float4*)W3)[lane];
    float a0 = v.x * w.x + v.y * w.z;
    float a1 = v.x * w.y + v.y * w.w;
#pragma unroll
    for (int off = 32; off > 0; off >>= 1) {
        a0 += __shfl_down(a0, off);
        a1 += __shfl_down(a1, off);
    }
    if (lane == 0) {
        out[(size_t)wid * 2]     = a0 + b3[0];
        out[(size_t)wid * 2 + 1] = a1 + b3[1];
    }
}

// ---------------------------------------------------------------------------
extern "C" void kernel_launch(void* const* d_in, const int* in_sizes, int n_in,
                              void* d_out, int out_size, void* d_ws, size_t ws_size,
                              hipStream_t stream) {
    const float* x   = (const float*)d_in[0];
    const int*   ei  = (const int*)d_in[1];
    const int*   src = ei;
    const int*   dst = ei + N_EDGES;
    const float* W1 = (const float*)d_in[2];
    const float* b1 = (const float*)d_in[3];
    const float* W2 = (const float*)d_in[4];
    const float* b2 = (const float*)d_in[5];
    const float* W3 = (const float*)d_in[6];
    const float* b3 = (const float*)d_in[7];
    float* out = (float*)d_out;

    char* base = (char*)d_ws;
    size_t off = 0;
    auto take = [&](size_t bytes) -> char* {
        char* p = base + off;
        off += (bytes + 255) & ~(size_t)255;
        return p;
    };
    int*            cnt    = (int*)           take(N_NODES * sizeof(int));
    unsigned short* bucket = (unsigned short*)take((size_t)N_NODES * CAP * sizeof(unsigned short));
    float*          y      = (float*)         take((size_t)N_NODES * F * sizeof(float));
    float*          h      = (float*)         take((size_t)N_NODES * F * sizeof(float));

    hipMemsetAsync(cnt, 0, N_NODES * sizeof(int), stream);

    // layer 1 GEMM (y = x@W1) overlapped with XCD-local uint16 bucket build
    gemm_bucket_kernel<<<GEMM_BLOCKS + SCAT_BLOCKS, 256, 0, stream>>>(
        x, W1, y, src, dst, cnt, bucket);
    // h = relu(mean(y) + b1)
    slice_agg_kernel<<<AGG_BLOCKS, 256, 0, stream>>>(y, cnt, bucket, b1, h);
    // y = h @ W2
    gemm_kernel<<<N_NODES / 32, 256, 0, stream>>>(h, W2, y);
    // h = relu(mean(y) + b2)
    slice_agg_kernel<<<AGG_BLOCKS, 256, 0, stream>>>(y, cnt, bucket, b2, h);
    // out = h @ W3 + b3
    final_kernel<<<(N_NODES * 64) / 256, 256, 0, stream>>>(h, W3, b3, out);
}

// Round 3
// 185.803 us; speedup vs baseline: 1.0223x; 1.0096x over previous
//
#include <hip/hip_runtime.h>

#define N_NODES 20000
#define N_EDGES 640000
#define F 128
#define CAP 128          // max in-degree; deg ~ Binomial(640K, 1/20K); expected max deg ~57
#define GEMM_BLOCKS (N_NODES / 32)     // 625
#define SCAT_BLOCKS 2560               // 320 per XCD residue class
#define QSTRIDE (SCAT_BLOCKS / 8 * 256)       // 81920 quad-stride per class
#define NODES_PER_XCD (N_NODES / 8)    // 2500
#define AGG_BLOCKS 2504                // 313 per residue class (last wave-set guarded)

// HISTORY:
//  r2/r3: fused GEMM+proj epilogue spilled (64-VGPR cap; VGPR=256 + 565 MB scratch).
//  r4: de-fused: 218. r5: gather-into-GEMM fusion -> occ 22.6%: 227 (revert).
//  r6: mean-linearity reorder (GEMM first): 215. r7: gemm1+bucket merge: 213.
//  r8: uint16 bucket + slice-partitioned agg (4 x 32-float slices, bid%8 XCD swizzle): 203.
//  r9: proj fused into agg2 via atomicAdd: 207.5 (regression, REVERTED).
//  r10: register-held index lists (shfl-distributed) + 2 nodes/wave agg: 187.4.
//  r11: XCD-LOCAL SCATTER (address-partitioned dst ranges): 185.9.
//  r12: group-per-node agg (no cross-lane ops): 189.9 NEUTRAL.
//  r13: int4 index load + 8-deep gather MLP in agg: 187.6 NEUTRAL.
//       Post-mortem r12/r13: agg redesigns don't move the needle -> agg is
//       not the proven bottleneck. gemm_bucket IS measured: 45.8 us, HBM 16%,
//       VALU 12.8%, occ 47% -> issue/latency-bound scatter scan (8x redundant
//       edge read = 5.1M scalar iters ~ 17 us of pure issue + L3-hit latency).
//  r14: VECTORIZED EDGE SCAN. Scatter reads int4 of dst/src (4 edges/iter,
//       16B/lane coalesced): scan issue count ~3x down, per-thread trip ~2.
//       Atomics, bucket locality, all other kernels unchanged.

// ---------------------------------------------------------------------------
// Merged: blocks [0,625) y = A @ W (proven 44-VGPR tile); blocks [625,3185)
// XCD-local scatter of edges into per-destination uint16 buckets.
// ---------------------------------------------------------------------------
__global__ __launch_bounds__(256)
void gemm_bucket_kernel(const float* __restrict__ A, const float* __restrict__ W,
                        float* __restrict__ C,
                        const int* __restrict__ src, const int* __restrict__ dst,
                        int* __restrict__ cnt, unsigned short* __restrict__ bucket) {
    __shared__ float As[32][F + 4];
    int tid = threadIdx.x;
    int bid = blockIdx.x;

    if (bid >= GEMM_BLOCKS) {
        int s   = bid - GEMM_BLOCKS;   // 0..2559
        int g   = bid & 7;             // XCD residue of the RAW block id
        int idx = s >> 3;              // 0..319 within this residue class
        int lo  = g * NODES_PER_XCD;
        int hi  = lo + NODES_PER_XCD;
        const int4* dst4 = (const int4*)dst;
        const int4* src4 = (const int4*)src;
        for (int q = idx * 256 + tid; q < N_EDGES / 4; q += QSTRIDE) {
            int4 d4 = dst4[q];         // 4 edges, one coalesced 16B load
            int4 s4 = src4[q];
            if (d4.x >= lo && d4.x < hi) {
                int pos = atomicAdd(&cnt[d4.x], 1);
                if (pos < CAP) bucket[(size_t)d4.x * CAP + pos] = (unsigned short)s4.x;
            }
            if (d4.y >= lo && d4.y < hi) {
                int pos = atomicAdd(&cnt[d4.y], 1);
                if (pos < CAP) bucket[(size_t)d4.y * CAP + pos] = (unsigned short)s4.y;
            }
            if (d4.z >= lo && d4.z < hi) {
                int pos = atomicAdd(&cnt[d4.z], 1);
                if (pos < CAP) bucket[(size_t)d4.z * CAP + pos] = (unsigned short)s4.z;
            }
            if (d4.w >= lo && d4.w < hi) {
                int pos = atomicAdd(&cnt[d4.w], 1);
                if (pos < CAP) bucket[(size_t)d4.w * CAP + pos] = (unsigned short)s4.w;
            }
        }
        return;
    }

    int row0 = bid * 32;
    const float4* A4 = (const float4*)(A + (size_t)row0 * F);
    for (int i = tid; i < 32 * 32; i += 256) {
        float4 v = A4[i];
        int r = i >> 5, c4 = (i & 31) * 4;
        *(float4*)&As[r][c4] = v;
    }
    __syncthreads();

    int tx = tid & 31, ty = tid >> 5;
    int c0 = tx * 4, r0 = ty * 4;
    float acc[4][4] = {};

    for (int k = 0; k < F; k += 4) {
        float4 a4[4];
#pragma unroll
        for (int i = 0; i < 4; ++i) a4[i] = *(const float4*)&As[r0 + i][k];
#pragma unroll
        for (int u = 0; u < 4; ++u) {
            float4 w = *(const float4*)(W + (size_t)(k + u) * F + c0);
#pragma unroll
            for (int i = 0; i < 4; ++i) {
                float a = (u == 0) ? a4[i].x : (u == 1) ? a4[i].y : (u == 2) ? a4[i].z : a4[i].w;
                acc[i][0] += a * w.x;
                acc[i][1] += a * w.y;
                acc[i][2] += a * w.z;
                acc[i][3] += a * w.w;
            }
        }
    }

#pragma unroll
    for (int i = 0; i < 4; ++i) {
        float4 o;
        o.x = acc[i][0]; o.y = acc[i][1]; o.z = acc[i][2]; o.w = acc[i][3];
        *(float4*)(C + (size_t)(row0 + r0 + i) * F + c0) = o;
    }
}

// ---------------------------------------------------------------------------
// Plain GEMM (layer 2): C = A @ W.
// ---------------------------------------------------------------------------
__global__ __launch_bounds__(256)
void gemm_kernel(const float* __restrict__ A, const float* __restrict__ W,
                 float* __restrict__ C) {
    __shared__ float As[32][F + 4];
    int tid  = threadIdx.x;
    int row0 = blockIdx.x * 32;

    const float4* A4 = (const float4*)(A + (size_t)row0 * F);
    for (int i = tid; i < 32 * 32; i += 256) {
        float4 v = A4[i];
        int r = i >> 5, c4 = (i & 31) * 4;
        *(float4*)&As[r][c4] = v;
    }
    __syncthreads();

    int tx = tid & 31, ty = tid >> 5;
    int c0 = tx * 4, r0 = ty * 4;
    float acc[4][4] = {};

    for (int k = 0; k < F; k += 4) {
        float4 a4[4];
#pragma unroll
        for (int i = 0; i < 4; ++i) a4[i] = *(const float4*)&As[r0 + i][k];
#pragma unroll
        for (int u = 0; u < 4; ++u) {
            float4 w = *(const float4*)(W + (size_t)(k + u) * F + c0);
#pragma unroll
            for (int i = 0; i < 4; ++i) {
                float a = (u == 0) ? a4[i].x : (u == 1) ? a4[i].y : (u == 2) ? a4[i].z : a4[i].w;
                acc[i][0] += a * w.x;
                acc[i][1] += a * w.y;
                acc[i][2] += a * w.z;
                acc[i][3] += a * w.w;
            }
        }
    }

#pragma unroll
    for (int i = 0; i < 4; ++i) {
        float4 o;
        o.x = acc[i][0]; o.y = acc[i][1]; o.z = acc[i][2]; o.w = acc[i][3];
        *(float4*)(C + (size_t)(row0 + r0 + i) * F + c0) = o;
    }
}

// ---------------------------------------------------------------------------
// Group-per-node slice aggregation + bias + relu:
//   out[n, slice] = relu(mean_{j in nbrs(n)} y[j, slice] + b[slice])
// One 8-lane group owns one node's full 32-float slice (8 lanes x float4).
// int4 index load (8 idx / 1 load latency) feeding 8 independent 128-B
// gathers; dual accumulators. Grid AGG_BLOCKS x 256; slice = (bid&7)&3,
// address-partitioned so correctness never depends on XCD mapping.
// ---------------------------------------------------------------------------
__global__ __launch_bounds__(256)
void slice_agg_kernel(const float* __restrict__ y, const int* __restrict__ cnt,
                      const unsigned short* __restrict__ bucket,
                      const float* __restrict__ b, float* __restrict__ out) {
    int bid   = blockIdx.x;
    int g     = bid & 7;
    int i     = bid >> 3;          // 0..312
    int slice = g & 3;
    int jj    = i * 2 + (g >> 2);  // 0..625 (625 -> guarded out)
    int wave  = threadIdx.x >> 6;
    int lane  = threadIdx.x & 63;
    int r     = lane >> 3;         // group id: which node
    int c4    = lane & 7;          // float4 column within slice

    int node_base = jj * 32 + wave * 8;
    if (node_base >= N_NODES) return;   // whole wave uniform (20000 % 8 == 0)
    int node = node_base + r;

    int deg = cnt[node];
    int d   = deg < CAP ? deg : CAP;
    const int4* lst4 = (const int4*)(bucket + (size_t)node * CAP);  // 8 idx / int4
    const int*  lst  = (const int*)lst4;                            // 2 idx / word

    const float4* fb = (const float4*)y + slice * 8 + c4;   // row stride 32 float4

    float4 acc0; acc0.x = acc0.y = acc0.z = acc0.w = 0.f;
    float4 acc1; acc1.x = acc1.y = acc1.z = acc1.w = 0.f;
    int c = 0;
    for (; c + 8 <= d; c += 8) {
        int4 w = lst4[c >> 3];                 // 8 indices, one load latency
        int i0 = w.x & 0xffff, i1 = (w.x >> 16) & 0xffff;
        int i2 = w.y & 0xffff, i3 = (w.y >> 16) & 0xffff;
        int i4 = w.z & 0xffff, i5 = (w.z >> 16) & 0xffff;
        int i6 = w.w & 0xffff, i7 = (w.w >> 16) & 0xffff;
        float4 v0 = fb[(size_t)i0 * 32];       // 8 independent 128-B gathers
        float4 v1 = fb[(size_t)i1 * 32];
        float4 v2 = fb[(size_t)i2 * 32];
        float4 v3 = fb[(size_t)i3 * 32];
        float4 v4 = fb[(size_t)i4 * 32];
        float4 v5 = fb[(size_t)i5 * 32];
        float4 v6 = fb[(size_t)i6 * 32];
        float4 v7 = fb[(size_t)i7 * 32];
        acc0.x += (v0.x + v1.x) + (v2.x + v3.x);
        acc0.y += (v0.y + v1.y) + (v2.y + v3.y);
        acc0.z += (v0.z + v1.z) + (v2.z + v3.z);
        acc0.w += (v0.w + v1.w) + (v2.w + v3.w);
        acc1.x += (v4.x + v5.x) + (v6.x + v7.x);
        acc1.y += (v4.y + v5.y) + (v6.y + v7.y);
        acc1.z += (v4.z + v5.z) + (v6.z + v7.z);
        acc1.w += (v4.w + v5.w) + (v6.w + v7.w);
    }
    for (; c < d; ++c) {
        int w   = lst[c >> 1];
        int idx = (c & 1) ? ((w >> 16) & 0xffff) : (w & 0xffff);
        float4 v = fb[(size_t)idx * 32];
        acc0.x += v.x; acc0.y += v.y; acc0.z += v.z; acc0.w += v.w;
    }
    acc0.x += acc1.x; acc0.y += acc1.y; acc0.z += acc1.z; acc0.w += acc1.w;

    float4 bv = ((const float4*)b)[slice * 8 + c4];
    float inv = 1.0f / fmaxf((float)deg, 1.0f);
    float4 o;
    o.x = fmaxf(acc0.x * inv + bv.x, 0.f);
    o.y = fmaxf(acc0.y * inv + bv.y, 0.f);
    o.z = fmaxf(acc0.z * inv + bv.z, 0.f);
    o.w = fmaxf(acc0.w * inv + bv.w, 0.f);
    ((float4*)out)[(size_t)node * 32 + slice * 8 + c4] = o;
}

// ---------------------------------------------------------------------------
// out[N x 2] = h[N x 128] @ W3[128 x 2] + b3. One wave per node, shuffle
// reduce. Proven cheap (never in any top-5).
// ---------------------------------------------------------------------------
__global__ __launch_bounds__(256)
void final_kernel(const float* __restrict__ h, const float* __restrict__ W3,
                  const float* __restrict__ b3, float* __restrict__ out) {
    int wid  = (blockIdx.x * blockDim.x + threadIdx.x) >> 6;
    int lane = threadIdx.x & 63;
    if (wid >= N_NODES) return;
    float2 v = ((const float2*)h)[(size_t)wid * 64 + lane];
    float4 w = ((const float4*)W3)[lane];
    float a0 = v.x * w.x + v.y * w.z;
    float a1 = v.x * w.y + v.y * w.w;
#pragma unroll
    for (int off = 32; off > 0; off >>= 1) {
        a0 += __shfl_down(a0, off);
        a1 += __shfl_down(a1, off);
    }
    if (lane == 0) {
        out[(size_t)wid * 2]     = a0 + b3[0];
        out[(size_t)wid * 2 + 1] = a1 + b3[1];
    }
}

// ---------------------------------------------------------------------------
extern "C" void kernel_launch(void* const* d_in, const int* in_sizes, int n_in,
                              void* d_out, int out_size, void* d_ws, size_t ws_size,
                              hipStream_t stream) {
    const float* x   = (const float*)d_in[0];
    const int*   ei  = (const int*)d_in[1];
    const int*   src = ei;
    const int*   dst = ei + N_EDGES;
    const float* W1 = (const float*)d_in[2];
    const float* b1 = (const float*)d_in[3];
    const float* W2 = (const float*)d_in[4];
    const float* b2 = (const float*)d_in[5];
    const float* W3 = (const float*)d_in[6];
    const float* b3 = (const float*)d_in[7];
    float* out = (float*)d_out;

    char* base = (char*)d_ws;
    size_t off = 0;
    auto take = [&](size_t bytes) -> char* {
        char* p = base + off;
        off += (bytes + 255) & ~(size_t)255;
        return p;
    };
    int*            cnt    = (int*)           take(N_NODES * sizeof(int));
    unsigned short* bucket = (unsigned short*)take((size_t)N_NODES * CAP * sizeof(unsigned short));
    float*          y      = (float*)         take((size_t)N_NODES * F * sizeof(float));
    float*          h      = (float*)         take((size_t)N_NODES * F * sizeof(float));

    hipMemsetAsync(cnt, 0, N_NODES * sizeof(int), stream);

    // layer 1 GEMM (y = x@W1) overlapped with XCD-local uint16 bucket build
    gemm_bucket_kernel<<<GEMM_BLOCKS + SCAT_BLOCKS, 256, 0, stream>>>(
        x, W1, y, src, dst, cnt, bucket);
    // h = relu(mean(y) + b1)
    slice_agg_kernel<<<AGG_BLOCKS, 256, 0, stream>>>(y, cnt, bucket, b1, h);
    // y = h @ W2
    gemm_kernel<<<N_NODES / 32, 256, 0, stream>>>(h, W2, y);
    // h = relu(mean(y) + b2)
    slice_agg_kernel<<<AGG_BLOCKS, 256, 0, stream>>>(y, cnt, bucket, b2, h);
    // out = h @ W3 + b3
    final_kernel<<<(N_NODES * 64) / 256, 256, 0, stream>>>(h, W3, b3, out);
}